// Round 10
// baseline (400.336 us; speedup 1.0000x reference)
//
#include <hip/hip_runtime.h>
#include <hip/hip_bf16.h>
#include <float.h>
#include <math.h>

#define KEY_DIM   512
#define VALUE_DIM 128
#define CAPACITY  500000
#define NRET      16

#define NBLK3      1024                    // sim blocks; 4 blocks/CU resident
#define NWV        (NBLK3*4)               // 4096 waves
#define SWEEP_ROWS (NWV*2)                 // 8192 rows per sweep
#define NSWEEP     61                      // 61*8192 = 499712 rows
#define TAILW      ((CAPACITY - NSWEEP*SWEEP_ROWS)/2)  // 144 waves take tail pair
#define SWEEPB     ((size_t)SWEEP_ROWS * KEY_DIM * 4)  // 16 MB

typedef float f32x4 __attribute__((ext_vector_type(4)));

__device__ __forceinline__ float wave_sum(float x) {
#pragma unroll
    for (int s = 32; s > 0; s >>= 1) x += __shfl_xor(x, s);
    return x;
}

// ---------------- Kernel 1a/1b: y[r] = act(dot(W[r,:], x) + b[r]) ----------
template <bool SILU>
__global__ __launch_bounds__(256) void matvec512(
        const float* __restrict__ W, const float* __restrict__ x,
        const float* __restrict__ b, float* __restrict__ y) {
    const int wid  = threadIdx.x >> 6;
    const int lane = threadIdx.x & 63;
    const int r = blockIdx.x * 4 + wid;          // 0..511

    const float4* Wr = (const float4*)(W + (size_t)r * KEY_DIM);
    const float4* xv = (const float4*)x;

    float4 w0 = Wr[lane], w1 = Wr[lane + 64];
    float4 x0 = xv[lane], x1 = xv[lane + 64];

    float dot = w0.x * x0.x + w0.y * x0.y + w0.z * x0.z + w0.w * x0.w
              + w1.x * x1.x + w1.y * x1.y + w1.z * x1.z + w1.w * x1.w;
    dot = wave_sum(dot);

    if (lane == 0) {
        float v = dot + b[r];
        if (SILU) v = v / (1.0f + expf(-v));     // silu = x*sigmoid(x)
        y[r] = v;
    }
}

// ---------------- Kernel 1c: LayerNorm + l2-normalize -> qn[512] -----------
__global__ __launch_bounds__(512) void ln_l2norm(
        const float* __restrict__ h, const float* __restrict__ gamma,
        const float* __restrict__ beta, float* __restrict__ qn) {
    __shared__ float s1[8], s2[8];
    const int t = threadIdx.x;                   // 512 threads = 8 waves
    const int wid = t >> 6, lane = t & 63;

    float x = h[t];
    float a = x, bb = x * x;
#pragma unroll
    for (int s = 32; s > 0; s >>= 1) { a += __shfl_xor(a, s); bb += __shfl_xor(bb, s); }
    if (lane == 0) { s1[wid] = a; s2[wid] = bb; }
    __syncthreads();

    float suma = 0.f, sumb = 0.f;
#pragma unroll
    for (int i = 0; i < 8; ++i) { suma += s1[i]; sumb += s2[i]; }
    float mu  = suma * (1.0f / KEY_DIM);
    float var = sumb * (1.0f / KEY_DIM) - mu * mu;      // biased, like torch LN
    float ln  = (x - mu) / sqrtf(var + 1e-5f) * gamma[t] + beta[t];

    float c = wave_sum(ln * ln);
    __syncthreads();
    if (lane == 0) s1[wid] = c;
    __syncthreads();
    float ss = 0.f;
#pragma unroll
    for (int i = 0; i < 8; ++i) ss += s1[i];
    float n = fmaxf(sqrtf(ss), 1e-12f);
    qn[t] = ln / n;
}

// ---------------- Kernel 2: register-streamed cosine sim + block top-16 ----
// No LDS staging: inline-asm global_load_dwordx4 -> VGPR double buffer.
// Wave owns 2 consecutive rows/iter; lane (h=lane>>5, m=lane&31) loads
// row h, float4-col 32j+m -> each instruction = 2 x 512B dense segments.
// One asm block issues 4 loads (offsets 0/512/1024/1536); explicit
// s_waitcnt vmcnt(4) + sched_barrier orders consumption (compiler sees no
// loads -> no stray vmcnt(0)). ~100 VGPR -> 16 waves/CU, 64-128 KB/CU in
// flight through the normal vector-return (MSHR) path.

__device__ __forceinline__ void ld4(f32x4 (&k)[4], const char* a) {
    asm volatile(
        "global_load_dwordx4 %0, %4, off\n\t"
        "global_load_dwordx4 %1, %4, off offset:512\n\t"
        "global_load_dwordx4 %2, %4, off offset:1024\n\t"
        "global_load_dwordx4 %3, %4, off offset:1536"
        : "=&v"(k[0]), "=&v"(k[1]), "=&v"(k[2]), "=&v"(k[3])
        : "v"(a)
        : "memory");
}

#define WAITN(N) do { asm volatile("s_waitcnt vmcnt(" #N ")" ::: "memory"); \
                      __builtin_amdgcn_sched_barrier(0); } while (0)

__device__ __forceinline__ void proc(const f32x4 (&k)[4], const f32x4 (&qr)[4],
                                     int rowbase, float (&v)[16], int (&id)[16]) {
    float dot = 0.f, ss = 0.f;
#pragma unroll
    for (int j = 0; j < 4; ++j) {
        f32x4 kk = k[j], qq = qr[j];
        dot += kk.x * qq.x + kk.y * qq.y + kk.z * qq.z + kk.w * qq.w;
        ss  += kk.x * kk.x + kk.y * kk.y + kk.z * kk.z + kk.w * kk.w;
    }
#pragma unroll
    for (int s = 16; s > 0; s >>= 1) {           // 32-lane segment reduce
        dot += __shfl_xor(dot, s);
        ss  += __shfl_xor(ss, s);
    }
    float sim = dot / fmaxf(sqrtf(ss), 1e-12f);
#pragma unroll
    for (int h = 0; h < 2; ++h) {
        float sq = __shfl(sim, h * 32);          // wave-uniform
        if (sq > v[15]) {
            float cv = sq; int ci = rowbase + h;
#pragma unroll
            for (int jj = 0; jj < 16; ++jj) {
                if (cv > v[jj]) {
                    float tv = v[jj]; int ti = id[jj];
                    v[jj] = cv; id[jj] = ci; cv = tv; ci = ti;
                }
            }
        }
    }
}

__global__ __launch_bounds__(256) void sim_topk(
        const float* __restrict__ keys, const float* __restrict__ qn,
        float* __restrict__ cand_v, int* __restrict__ cand_i) {
    __shared__ float bv[64];
    __shared__ int   bi[64];

    const int tid  = threadIdx.x;
    const int w    = tid >> 6;
    const int lane = tid & 63;
    const int m    = lane & 31;
    const int h    = lane >> 5;
    const int gw   = blockIdx.x * 4 + w;         // 0..4095

    // q fragment: float4 cols {32j + m}
    f32x4 qr[4];
    {
        const f32x4* q4 = (const f32x4*)qn;
#pragma unroll
        for (int j = 0; j < 4; ++j) qr[j] = q4[32 * j + m];
    }

    // wave-uniform top-16
    float v[16]; int id[16];
#pragma unroll
    for (int j = 0; j < 16; ++j) { v[j] = -FLT_MAX; id[j] = 0x7fffffff; }

    // per-lane base address: row gw*2+h, byte col m*16
    const char* base = (const char*)keys
                     + ((size_t)(gw * 2 + h)) * (KEY_DIM * 4) + (size_t)m * 16;
    const char* aA = base;                        // even sweeps
    const char* aB = base + SWEEPB;               // odd sweeps

    f32x4 kA[4], kB[4];
    int rb = gw * 2;                              // rowbase for sweep 0

    ld4(kA, aA); aA += 2 * SWEEPB;                // sweep 0

#pragma unroll 1
    for (int p = 0; p < 29; ++p) {                // computes sweeps 0..57
        ld4(kB, aB); aB += 2 * SWEEPB;            // sweep 2p+1
        WAITN(4);
        proc(kA, qr, rb, v, id); rb += SWEEP_ROWS;
        ld4(kA, aA); aA += 2 * SWEEPB;            // sweep 2p+2
        WAITN(4);
        proc(kB, qr, rb, v, id); rb += SWEEP_ROWS;
    }
    ld4(kB, aB);                                  // sweep 59
    WAITN(4);
    proc(kA, qr, rb, v, id); rb += SWEEP_ROWS;    // sweep 58
    ld4(kA, aA);                                  // sweep 60
    WAITN(4);
    proc(kB, qr, rb, v, id); rb += SWEEP_ROWS;    // sweep 59
    WAITN(0);
    proc(kA, qr, rb, v, id);                      // sweep 60

    // tail: rows 499712..499999 -> waves 0..143, one extra pair
    if (gw < TAILW) {
        const int trow = NSWEEP * SWEEP_ROWS + gw * 2;
        const char* at = (const char*)keys
                       + ((size_t)(trow + h)) * (KEY_DIM * 4) + (size_t)m * 16;
        ld4(kB, at);
        WAITN(0);
        proc(kB, qr, trow, v, id);
    }

    // ---- merge 4 waves' top-16 -> block top-16 ----------------------------
    if (lane == 0) {
#pragma unroll
        for (int j = 0; j < 16; ++j) { bv[w * 16 + j] = v[j]; bi[w * 16 + j] = id[j]; }
    }
    __syncthreads();
    if (w == 0) {
        float lv = bv[lane]; int li = bi[lane];
        for (int rr = 0; rr < NRET; ++rr) {
            float mv = lv; int mi = li;
#pragma unroll
            for (int s = 32; s > 0; s >>= 1) {
                float ov = __shfl_xor(mv, s); int oi = __shfl_xor(mi, s);
                if (ov > mv || (ov == mv && oi < mi)) { mv = ov; mi = oi; }
            }
            if (lane == 0) {
                cand_v[blockIdx.x * NRET + rr] = mv;
                cand_i[blockIdx.x * NRET + rr] = mi;
            }
            if (lv == mv && li == mi) { lv = -FLT_MAX; li = 0x7fffffff; }
        }
    }
}

// ---------------- Kernel 3: final top-16 + softmax + gather ----------------
__global__ __launch_bounds__(256) void merge_out(
        const float* __restrict__ cand_v, const int* __restrict__ cand_i,
        const float* __restrict__ values, float* __restrict__ out) {
    const int tid  = threadIdx.x;
    const int wid  = tid >> 6;
    const int lane = tid & 63;
    const int M4 = (NBLK3 * NRET) / 4;           // 4096 float4 groups

    float v[16]; int id[16];
#pragma unroll
    for (int j = 0; j < 16; ++j) { v[j] = -FLT_MAX; id[j] = 0x7fffffff; }

    const float4* cv4 = (const float4*)cand_v;
    const int4*   ci4 = (const int4*)cand_i;
    for (int c = tid; c < M4; c += 256) {        // 16 iterations
        float4 cv = cv4[c]; int4 ci = ci4[c];
        float cvs[4] = {cv.x, cv.y, cv.z, cv.w};
        int   cis[4] = {ci.x, ci.y, ci.z, ci.w};
#pragma unroll
        for (int u = 0; u < 4; ++u) {
            float cu = cvs[u]; int iu = cis[u];
            if (cu > v[15]) {
#pragma unroll
                for (int j = 0; j < 16; ++j) {
                    if (cu > v[j]) {
                        float tv = v[j]; int ti = id[j];
                        v[j] = cu; id[j] = iu; cu = tv; iu = ti;
                    }
                }
            }
        }
    }

    __shared__ float sv[64];
    __shared__ int   si[64];
    for (int rr = 0; rr < NRET; ++rr) {
        float mv = v[0]; int mi = id[0];
#pragma unroll
        for (int s = 32; s > 0; s >>= 1) {
            float ov = __shfl_xor(mv, s); int oi = __shfl_xor(mi, s);
            if (ov > mv || (ov == mv && oi < mi)) { mv = ov; mi = oi; }
        }
        if (v[0] == mv && id[0] == mi) {
#pragma unroll
            for (int j = 0; j < 15; ++j) { v[j] = v[j + 1]; id[j] = id[j + 1]; }
            v[15] = -FLT_MAX; id[15] = 0x7fffffff;
        }
        if (lane == 0) { sv[wid * 16 + rr] = mv; si[wid * 16 + rr] = mi; }
    }
    __syncthreads();

    if (wid == 0) {
        float lv = sv[lane]; int li = si[lane];
        float sel_v = -FLT_MAX; int sel_i = 0;
        for (int rr = 0; rr < NRET; ++rr) {
            float mv = lv; int mi = li;
#pragma unroll
            for (int s = 32; s > 0; s >>= 1) {
                float ov = __shfl_xor(mv, s); int oi = __shfl_xor(mi, s);
                if (ov > mv || (ov == mv && oi < mi)) { mv = ov; mi = oi; }
            }
            if (lv == mv && li == mi) { lv = -FLT_MAX; li = 0x7fffffff; }
            if (lane == rr) { sel_v = mv; sel_i = mi; }
        }

        // softmax over the 16 (lane 0 holds the max: rounds are descending)
        float m0 = __shfl(sel_v, 0);
        float e = (lane < NRET) ? expf(sel_v - m0) : 0.0f;
        float denom = wave_sum(e);

        float acc0 = 0.f, acc1 = 0.f;
        for (int rr = 0; rr < NRET; ++rr) {
            float ar = __shfl(e, rr) / denom;
            int   ir = __shfl(sel_i, rr);
            const float* vr = values + (size_t)ir * VALUE_DIM;
            acc0 += ar * vr[lane];
            acc1 += ar * vr[lane + 64];
        }
        out[lane]      = acc0;
        out[lane + 64] = acc1;
    }
}

extern "C" void kernel_launch(void* const* d_in, const int* in_sizes, int n_in,
                              void* d_out, int out_size, void* d_ws, size_t ws_size,
                              hipStream_t stream) {
    const float* query  = (const float*)d_in[0];
    const float* W1     = (const float*)d_in[1];
    const float* b1     = (const float*)d_in[2];
    const float* W2     = (const float*)d_in[3];
    const float* b2     = (const float*)d_in[4];
    const float* gamma  = (const float*)d_in[5];
    const float* beta   = (const float*)d_in[6];
    const float* keys   = (const float*)d_in[7];
    const float* values = (const float*)d_in[8];
    float* out = (float*)d_out;

    float* ws = (float*)d_ws;
    float* h1     = ws;                  // 512
    float* h2     = ws + 512;            // 512
    float* qn     = ws + 1024;           // 512
    float* cand_v = ws + 2048;           // NBLK3*16 floats
    int*   cand_i = (int*)(ws + 2048 + NBLK3 * NRET);

    matvec512<true ><<<128, 256, 0, stream>>>(W1, query, b1, h1);
    matvec512<false><<<128, 256, 0, stream>>>(W2, h1, b2, h2);
    ln_l2norm<<<1, 512, 0, stream>>>(h2, gamma, beta, qn);
    sim_topk<<<NBLK3, 256, 0, stream>>>(keys, qn, cand_v, cand_i);
    merge_out<<<1, 256, 0, stream>>>(cand_v, cand_i, values, out);
}

// Round 12
// 313.132 us; speedup vs baseline: 1.2785x; 1.2785x over previous
//
#include <hip/hip_runtime.h>
#include <hip/hip_bf16.h>
#include <float.h>
#include <math.h>

#define KEY_DIM   512
#define VALUE_DIM 128
#define CAPACITY  500000
#define NRET      16

// hybrid sim config
#define NBLKD     512                      // DMA-path blocks (R9 structure, ring-3)
#define NBLKV     256                      // vector-path blocks (R2 structure)
#define NBLKT     (NBLKD + NBLKV)          // 768 total
#define NSD       70                       // DMA sub-tiles per block (uniform)
#define NDROWS    (NBLKD * NSD * 8)        // 286720 rows via DMA path
#define ROFF      NDROWS                   // vector path offset
#define NVROWS    (CAPACITY - NDROWS)      // 213280 rows via vector path (div by 4)
#define VSWEEP    (NBLKV * 4 * 4)          // 4096 rows per vector sweep (FIXED R11 bug)
#define RING      3

#define AS3 __attribute__((address_space(3)))
#define AS1 __attribute__((address_space(1)))

__device__ __forceinline__ float wave_sum(float x) {
#pragma unroll
    for (int s = 32; s > 0; s >>= 1) x += __shfl_xor(x, s);
    return x;
}

// ---------------- Kernel 1a/1b: y[r] = act(dot(W[r,:], x) + b[r]) ----------
template <bool SILU>
__global__ __launch_bounds__(256) void matvec512(
        const float* __restrict__ W, const float* __restrict__ x,
        const float* __restrict__ b, float* __restrict__ y) {
    const int wid  = threadIdx.x >> 6;
    const int lane = threadIdx.x & 63;
    const int r = blockIdx.x * 4 + wid;          // 0..511

    const float4* Wr = (const float4*)(W + (size_t)r * KEY_DIM);
    const float4* xv = (const float4*)x;

    float4 w0 = Wr[lane], w1 = Wr[lane + 64];
    float4 x0 = xv[lane], x1 = xv[lane + 64];

    float dot = w0.x * x0.x + w0.y * x0.y + w0.z * x0.z + w0.w * x0.w
              + w1.x * x1.x + w1.y * x1.y + w1.z * x1.z + w1.w * x1.w;
    dot = wave_sum(dot);

    if (lane == 0) {
        float v = dot + b[r];
        if (SILU) v = v / (1.0f + expf(-v));     // silu = x*sigmoid(x)
        y[r] = v;
    }
}

// ---------------- Kernel 1c: LayerNorm + l2-normalize -> qn[512] -----------
__global__ __launch_bounds__(512) void ln_l2norm(
        const float* __restrict__ h, const float* __restrict__ gamma,
        const float* __restrict__ beta, float* __restrict__ qn) {
    __shared__ float s1[8], s2[8];
    const int t = threadIdx.x;                   // 512 threads = 8 waves
    const int wid = t >> 6, lane = t & 63;

    float x = h[t];
    float a = x, bb = x * x;
#pragma unroll
    for (int s = 32; s > 0; s >>= 1) { a += __shfl_xor(a, s); bb += __shfl_xor(bb, s); }
    if (lane == 0) { s1[wid] = a; s2[wid] = bb; }
    __syncthreads();

    float suma = 0.f, sumb = 0.f;
#pragma unroll
    for (int i = 0; i < 8; ++i) { suma += s1[i]; sumb += s2[i]; }
    float mu  = suma * (1.0f / KEY_DIM);
    float var = sumb * (1.0f / KEY_DIM) - mu * mu;      // biased, like torch LN
    float ln  = (x - mu) / sqrtf(var + 1e-5f) * gamma[t] + beta[t];

    float c = wave_sum(ln * ln);
    __syncthreads();
    if (lane == 0) s1[wid] = c;
    __syncthreads();
    float ss = 0.f;
#pragma unroll
    for (int i = 0; i < 8; ++i) ss += s1[i];
    float n = fmaxf(sqrtf(ss), 1e-12f);
    qn[t] = ln / n;
}

// ---------------- Kernel 2: HYBRID cosine sim + per-block top-16 -----------
// Two concurrent read paths, each proven separately, splitting the key range:
//  - bid%3<2 (512 blocks): R9 DMA structure (global_load_lds ring-3, 48 KB
//    LDS, wave-private sub-buffers, counted vmcnt, no barriers) -> 4.4 TB/s.
//  - bid%3==2 (256 blocks): R2 vector structure (4 batched rows/iter, plain
//    float4 loads, butterfly reduce) -> 3.2 TB/s.
// 48 KB static LDS/block -> 3 blocks/CU; round-robin dispatch gives each CU
// ~2 DMA + 1 vector block, so the two per-CU path caps add (theory under test).
__global__ __launch_bounds__(256) void sim_hybrid(
        const float* __restrict__ keys, const float* __restrict__ qn,
        float* __restrict__ cand_v, int* __restrict__ cand_i) {
    __shared__ float kl[RING][8][KEY_DIM];           // 48 KB (DMA blocks only)
    __shared__ float bv[64];
    __shared__ int   bi[64];

    const int tid  = threadIdx.x;
    const int w    = tid >> 6;
    const int lane = tid & 63;
    const int bid  = blockIdx.x;
    const int r3   = bid % 3;

    // wave-uniform top-16
    float v[16]; int id[16];
#pragma unroll
    for (int j = 0; j < 16; ++j) { v[j] = -FLT_MAX; id[j] = 0x7fffffff; }

    if (r3 < 2) {
        // ================= DMA path (R9 chassis, ring-3) ==================
        const int d    = (bid / 3) * 2 + r3;         // 0..511
        const int m    = lane & 31;
        const int rsel = lane >> 5;
        const int s0   = (d * 7919) % NSD;

        float4 qr[4];
        {
            const float4* q4 = (const float4*)qn;
#pragma unroll
            for (int j = 0; j < 4; ++j) qr[j] = q4[4 * m + j];
        }
        int srcoff0, srcoff1;
        {
            int p0 = lane,      g0 = p0 >> 2, sl0 = p0 & 3;
            int p1 = 64 + lane, g1 = p1 >> 2, sl1 = p1 & 3;
            srcoff0 = (4 * g0 + ((sl0 - (g0 >> 1)) & 3)) * 16;
            srcoff1 = (4 * g1 + ((sl1 - (g1 >> 1)) & 3)) * 16;
        }
        int roff[4];
#pragma unroll
        for (int j = 0; j < 4; ++j) roff[j] = (4 * m + ((j + (m >> 1)) & 3)) * 16;

        auto stage = [&](int G, int slot) {
#pragma unroll
            for (int i = 0; i < 4; ++i) {
                const int rl = 2 * w + (i >> 1);
                const int h  = i & 1;
                const char* gp = (const char*)(keys + ((size_t)G * 8 + rl) * KEY_DIM)
                                 + (h ? srcoff1 : srcoff0);
                float* lp = &kl[slot][rl][h * 256];  // wave-uniform base
                __builtin_amdgcn_global_load_lds((const AS1 float*)gp, (AS3 float*)lp,
                                                 16, 0, 0);
            }
        };
        auto compute = [&](int G, int slot) {
            const char* rowbase = (const char*)&kl[slot][2 * w + rsel][0];
            float dot = 0.f, ss = 0.f;
#pragma unroll
            for (int j = 0; j < 4; ++j) {
                float4 k = *(const float4*)(rowbase + roff[j]);
                float4 q = qr[j];
                dot += k.x * q.x + k.y * q.y + k.z * q.z + k.w * q.w;
                ss  += k.x * k.x + k.y * k.y + k.z * k.z + k.w * k.w;
            }
#pragma unroll
            for (int s = 16; s > 0; s >>= 1) {
                dot += __shfl_xor(dot, s);
                ss  += __shfl_xor(ss, s);
            }
            float sim = dot / fmaxf(sqrtf(ss), 1e-12f);
#pragma unroll
            for (int q = 0; q < 2; ++q) {
                float sq = __shfl(sim, q * 32);      // wave-uniform
                if (sq > v[15]) {
                    float cv = sq; int ci = G * 8 + 2 * w + q;
#pragma unroll
                    for (int jj = 0; jj < 16; ++jj) {
                        if (cv > v[jj]) {
                            float tv = v[jj]; int ti = id[jj];
                            v[jj] = cv; id[jj] = ci; cv = tv; ci = ti;
                        }
                    }
                }
            }
        };

        {   // prologue: seq s0, s0+1 -> slots 0,1
            int se = s0;
            stage(d + se * NBLKD, 0);
            se = (se + 1 >= NSD) ? 0 : se + 1;
            stage(d + se * NBLKD, 1);
        }
        int scur = s0;
        int spre = s0 + 2; if (spre >= NSD) spre -= NSD;

#pragma unroll 1
        for (int s = 0; s < NSD; ++s) {
            stage(d + spre * NBLKD, (s + 2) % 3);    // unconditional (wraps)
            spre = (spre + 1 >= NSD) ? 0 : spre + 1;
            asm volatile("s_waitcnt vmcnt(8)" ::: "memory");
            __builtin_amdgcn_sched_barrier(0);
            compute(d + scur * NBLKD, s % 3);
            __builtin_amdgcn_sched_barrier(0);
            scur = (scur + 1 >= NSD) ? 0 : scur + 1;
        }
        asm volatile("s_waitcnt vmcnt(0)" ::: "memory");
    } else {
        // ================= vector path (R2 chassis) =======================
        const int gw = (bid / 3) * 4 + w;            // 0..1023
        const float4* q4 = (const float4*)qn;
        float4 q0 = q4[lane], q1 = q4[lane + 64];

#pragma unroll 1
        for (int base = gw * 4; base < NVROWS; base += VSWEEP) {  // 4096/sweep
            float4 ka[4], kb[4];
#pragma unroll
            for (int j = 0; j < 4; ++j) {
                const float4* kp = (const float4*)(keys + (size_t)(ROFF + base + j) * KEY_DIM);
                ka[j] = kp[lane];
                kb[j] = kp[lane + 64];
            }
            float dot[4], ss[4];
#pragma unroll
            for (int j = 0; j < 4; ++j) {
                dot[j] = ka[j].x * q0.x + ka[j].y * q0.y + ka[j].z * q0.z + ka[j].w * q0.w
                       + kb[j].x * q1.x + kb[j].y * q1.y + kb[j].z * q1.z + kb[j].w * q1.w;
                ss[j]  = ka[j].x * ka[j].x + ka[j].y * ka[j].y + ka[j].z * ka[j].z + ka[j].w * ka[j].w
                       + kb[j].x * kb[j].x + kb[j].y * kb[j].y + kb[j].z * kb[j].z + kb[j].w * kb[j].w;
            }
#pragma unroll
            for (int s = 32; s > 0; s >>= 1) {
#pragma unroll
                for (int j = 0; j < 4; ++j) {
                    dot[j] += __shfl_xor(dot[j], s);
                    ss[j]  += __shfl_xor(ss[j], s);
                }
            }
#pragma unroll
            for (int j = 0; j < 4; ++j) {
                float sim = dot[j] / fmaxf(sqrtf(ss[j]), 1e-12f);
                if (sim > v[15]) {                   // wave-uniform
                    float cv = sim; int ci = ROFF + base + j;
#pragma unroll
                    for (int jj = 0; jj < 16; ++jj) {
                        if (cv > v[jj]) {
                            float tv = v[jj]; int ti = id[jj];
                            v[jj] = cv; id[jj] = ci; cv = tv; ci = ti;
                        }
                    }
                }
            }
        }
    }

    // ---- merge 4 waves' top-16 -> block top-16 ----------------------------
    if (lane == 0) {
#pragma unroll
        for (int j = 0; j < 16; ++j) { bv[w * 16 + j] = v[j]; bi[w * 16 + j] = id[j]; }
    }
    __syncthreads();
    if (w == 0) {
        const int cidx = (r3 < 2) ? ((bid / 3) * 2 + r3) : (NBLKD + bid / 3);
        float lv = bv[lane]; int li = bi[lane];
        for (int rr = 0; rr < NRET; ++rr) {
            float mv = lv; int mi = li;
#pragma unroll
            for (int s = 32; s > 0; s >>= 1) {
                float ov = __shfl_xor(mv, s); int oi = __shfl_xor(mi, s);
                if (ov > mv || (ov == mv && oi < mi)) { mv = ov; mi = oi; }
            }
            if (lane == 0) {
                cand_v[cidx * NRET + rr] = mv;
                cand_i[cidx * NRET + rr] = mi;
            }
            if (lv == mv && li == mi) { lv = -FLT_MAX; li = 0x7fffffff; }
        }
    }
}

// ---------------- Kernel 3: final top-16 + softmax + gather ----------------
__global__ __launch_bounds__(256) void merge_out(
        const float* __restrict__ cand_v, const int* __restrict__ cand_i,
        const float* __restrict__ values, float* __restrict__ out) {
    const int tid  = threadIdx.x;
    const int wid  = tid >> 6;
    const int lane = tid & 63;
    const int M4 = (NBLKT * NRET) / 4;           // 3072 float4 groups

    float v[16]; int id[16];
#pragma unroll
    for (int j = 0; j < 16; ++j) { v[j] = -FLT_MAX; id[j] = 0x7fffffff; }

    const float4* cv4 = (const float4*)cand_v;
    const int4*   ci4 = (const int4*)cand_i;
    for (int c = tid; c < M4; c += 256) {        // 12 iterations
        float4 cv = cv4[c]; int4 ci = ci4[c];
        float cvs[4] = {cv.x, cv.y, cv.z, cv.w};
        int   cis[4] = {ci.x, ci.y, ci.z, ci.w};
#pragma unroll
        for (int u = 0; u < 4; ++u) {
            float cu = cvs[u]; int iu = cis[u];
            if (cu > v[15]) {
#pragma unroll
                for (int j = 0; j < 16; ++j) {
                    if (cu > v[j]) {
                        float tv = v[j]; int ti = id[j];
                        v[j] = cu; id[j] = iu; cu = tv; iu = ti;
                    }
                }
            }
        }
    }

    __shared__ float sv[64];
    __shared__ int   si[64];
    for (int rr = 0; rr < NRET; ++rr) {
        float mv = v[0]; int mi = id[0];
#pragma unroll
        for (int s = 32; s > 0; s >>= 1) {
            float ov = __shfl_xor(mv, s); int oi = __shfl_xor(mi, s);
            if (ov > mv || (ov == mv && oi < mi)) { mv = ov; mi = oi; }
        }
        if (v[0] == mv && id[0] == mi) {
#pragma unroll
            for (int j = 0; j < 15; ++j) { v[j] = v[j + 1]; id[j] = id[j + 1]; }
            v[15] = -FLT_MAX; id[15] = 0x7fffffff;
        }
        if (lane == 0) { sv[wid * 16 + rr] = mv; si[wid * 16 + rr] = mi; }
    }
    __syncthreads();

    if (wid == 0) {
        float lv = sv[lane]; int li = si[lane];
        float sel_v = -FLT_MAX; int sel_i = 0;
        for (int rr = 0; rr < NRET; ++rr) {
            float mv = lv; int mi = li;
#pragma unroll
            for (int s = 32; s > 0; s >>= 1) {
                float ov = __shfl_xor(mv, s); int oi = __shfl_xor(mi, s);
                if (ov > mv || (ov == mv && oi < mi)) { mv = ov; mi = oi; }
            }
            if (lv == mv && li == mi) { lv = -FLT_MAX; li = 0x7fffffff; }
            if (lane == rr) { sel_v = mv; sel_i = mi; }
        }

        // softmax over the 16 (lane 0 holds the max: rounds are descending)
        float m0 = __shfl(sel_v, 0);
        float e = (lane < NRET) ? expf(sel_v - m0) : 0.0f;
        float denom = wave_sum(e);

        float acc0 = 0.f, acc1 = 0.f;
        for (int rr = 0; rr < NRET; ++rr) {
            float ar = __shfl(e, rr) / denom;
            int   ir = __shfl(sel_i, rr);
            const float* vr = values + (size_t)ir * VALUE_DIM;
            acc0 += ar * vr[lane];
            acc1 += ar * vr[lane + 64];
        }
        out[lane]      = acc0;
        out[lane + 64] = acc1;
    }
}

extern "C" void kernel_launch(void* const* d_in, const int* in_sizes, int n_in,
                              void* d_out, int out_size, void* d_ws, size_t ws_size,
                              hipStream_t stream) {
    const float* query  = (const float*)d_in[0];
    const float* W1     = (const float*)d_in[1];
    const float* b1     = (const float*)d_in[2];
    const float* W2     = (const float*)d_in[3];
    const float* b2     = (const float*)d_in[4];
    const float* gamma  = (const float*)d_in[5];
    const float* beta   = (const float*)d_in[6];
    const float* keys   = (const float*)d_in[7];
    const float* values = (const float*)d_in[8];
    float* out = (float*)d_out;

    float* ws = (float*)d_ws;
    float* h1     = ws;                  // 512
    float* h2     = ws + 512;            // 512
    float* qn     = ws + 1024;           // 512
    float* cand_v = ws + 2048;           // NBLKT*16 floats
    int*   cand_i = (int*)(ws + 2048 + NBLKT * NRET);

    matvec512<true ><<<128, 256, 0, stream>>>(W1, query, b1, h1);
    matvec512<false><<<128, 256, 0, stream>>>(W2, h1, b2, h2);
    ln_l2norm<<<1, 512, 0, stream>>>(h2, gamma, beta, qn);
    sim_hybrid<<<NBLKT, 256, 0, stream>>>(keys, qn, cand_v, cand_i);
    merge_out<<<1, 256, 0, stream>>>(cand_v, cand_i, values, out);
}

// Round 13
// 272.504 us; speedup vs baseline: 1.4691x; 1.1491x over previous
//
#include <hip/hip_runtime.h>
#include <hip/hip_bf16.h>
#include <float.h>
#include <math.h>

#define KEY_DIM   512
#define VALUE_DIM 128
#define CAPACITY  500000
#define NRET      16

#define NBLKS     768                      // 3 blocks/CU (48.5 KB LDS each)
#define RING      4
#define NSD       87                       // DMA sub-tiles per block (uniform)
#define DROWS     (NBLKS * 6 * NSD)        // 400896 rows via DMA waves (0-2)
#define VOFF      DROWS
#define VSWEEP    (NBLKS * 4)              // 3072 rows per vector sweep (wave 3)

#define AS3 __attribute__((address_space(3)))
#define AS1 __attribute__((address_space(1)))

__device__ __forceinline__ float wave_sum(float x) {
#pragma unroll
    for (int s = 32; s > 0; s >>= 1) x += __shfl_xor(x, s);
    return x;
}

// ---------------- Kernel 1a/1b: y[r] = act(dot(W[r,:], x) + b[r]) ----------
template <bool SILU>
__global__ __launch_bounds__(256) void matvec512(
        const float* __restrict__ W, const float* __restrict__ x,
        const float* __restrict__ b, float* __restrict__ y) {
    const int wid  = threadIdx.x >> 6;
    const int lane = threadIdx.x & 63;
    const int r = blockIdx.x * 4 + wid;          // 0..511

    const float4* Wr = (const float4*)(W + (size_t)r * KEY_DIM);
    const float4* xv = (const float4*)x;

    float4 w0 = Wr[lane], w1 = Wr[lane + 64];
    float4 x0 = xv[lane], x1 = xv[lane + 64];

    float dot = w0.x * x0.x + w0.y * x0.y + w0.z * x0.z + w0.w * x0.w
              + w1.x * x1.x + w1.y * x1.y + w1.z * x1.z + w1.w * x1.w;
    dot = wave_sum(dot);

    if (lane == 0) {
        float v = dot + b[r];
        if (SILU) v = v / (1.0f + expf(-v));     // silu = x*sigmoid(x)
        y[r] = v;
    }
}

// ---------------- Kernel 1c: LayerNorm + l2-normalize -> qn[512] -----------
__global__ __launch_bounds__(512) void ln_l2norm(
        const float* __restrict__ h, const float* __restrict__ gamma,
        const float* __restrict__ beta, float* __restrict__ qn) {
    __shared__ float s1[8], s2[8];
    const int t = threadIdx.x;                   // 512 threads = 8 waves
    const int wid = t >> 6, lane = t & 63;

    float x = h[t];
    float a = x, bb = x * x;
#pragma unroll
    for (int s = 32; s > 0; s >>= 1) { a += __shfl_xor(a, s); bb += __shfl_xor(bb, s); }
    if (lane == 0) { s1[wid] = a; s2[wid] = bb; }
    __syncthreads();

    float suma = 0.f, sumb = 0.f;
#pragma unroll
    for (int i = 0; i < 8; ++i) { suma += s1[i]; sumb += s2[i]; }
    float mu  = suma * (1.0f / KEY_DIM);
    float var = sumb * (1.0f / KEY_DIM) - mu * mu;      // biased, like torch LN
    float ln  = (x - mu) / sqrtf(var + 1e-5f) * gamma[t] + beta[t];

    float c = wave_sum(ln * ln);
    __syncthreads();
    if (lane == 0) s1[wid] = c;
    __syncthreads();
    float ss = 0.f;
#pragma unroll
    for (int i = 0; i < 8; ++i) ss += s1[i];
    float n = fmaxf(sqrtf(ss), 1e-12f);
    qn[t] = ln / n;
}

// ---------------- Kernel 2: wave-split hybrid cosine sim -------------------
// 4 waves/block, 768 blocks (all resident, 3/CU):
//  - waves 0-2: R9 DMA chassis (global_load_lds ring-4, wave-private 2-row
//    slices, counted vmcnt(12), wrap-staged uniform waits, no barriers) over
//    rows [0, 400896). 9 DMA waves/CU (>= R9's 8 -> >= 17.2 GB/s/CU).
//  - wave 3:   R2 vector chassis (4 batched rows/iter, plain float4 loads,
//    butterfly reduce) over rows [400896, 500000). 3 vector waves/CU,
//    coresident the whole time (R12 decomposition: coresident rates ADD).
// Split 80:20 matches measured per-CU path rates so both finish together.
__global__ __launch_bounds__(256) void sim_split(
        const float* __restrict__ keys, const float* __restrict__ qn,
        float* __restrict__ cand_v, int* __restrict__ cand_i) {
    __shared__ float kl[RING][6][KEY_DIM];           // 48 KB (DMA ring)
    __shared__ float bv[64];
    __shared__ int   bi[64];

    const int tid  = threadIdx.x;
    const int w    = tid >> 6;
    const int lane = tid & 63;
    const int bid  = blockIdx.x;

    // wave-uniform top-16
    float v[16]; int id[16];
#pragma unroll
    for (int j = 0; j < 16; ++j) { v[j] = -FLT_MAX; id[j] = 0x7fffffff; }

    if (w < 3) {
        // ================= DMA path (R9 chassis, waves 0-2) ===============
        const int m    = lane & 31;                  // col-slice within row
        const int rsel = lane >> 5;                  // which of wave's 2 rows
        const int s0   = (bid * 7919) % NSD;

        float4 qr[4];
        {
            const float4* q4 = (const float4*)qn;
#pragma unroll
            for (int j = 0; j < 4; ++j) qr[j] = q4[4 * m + j];
        }
        int srcoff0, srcoff1;
        {
            int p0 = lane,      g0 = p0 >> 2, sl0 = p0 & 3;
            int p1 = 64 + lane, g1 = p1 >> 2, sl1 = p1 & 3;
            srcoff0 = (4 * g0 + ((sl0 - (g0 >> 1)) & 3)) * 16;
            srcoff1 = (4 * g1 + ((sl1 - (g1 >> 1)) & 3)) * 16;
        }
        int roff[4];
#pragma unroll
        for (int j = 0; j < 4; ++j) roff[j] = (4 * m + ((j + (m >> 1)) & 3)) * 16;

        // stage: wave w stages rows 2w,2w+1 of tile T into ring slot (4 loads)
        auto stage = [&](int T, int slot) {
#pragma unroll
            for (int i = 0; i < 4; ++i) {
                const int rl = 2 * w + (i >> 1);     // 0..5
                const int h  = i & 1;
                const char* gp = (const char*)(keys + ((size_t)T * 6 + rl) * KEY_DIM)
                                 + (h ? srcoff1 : srcoff0);
                float* lp = &kl[slot][rl][h * 256];  // wave-uniform base
                __builtin_amdgcn_global_load_lds((const AS1 float*)gp, (AS3 float*)lp,
                                                 16, 0, 0);
            }
        };
        auto compute = [&](int T, int slot) {
            const char* rowbase = (const char*)&kl[slot][2 * w + rsel][0];
            float dot = 0.f, ss = 0.f;
#pragma unroll
            for (int j = 0; j < 4; ++j) {
                float4 k = *(const float4*)(rowbase + roff[j]);
                float4 q = qr[j];
                dot += k.x * q.x + k.y * q.y + k.z * q.z + k.w * q.w;
                ss  += k.x * k.x + k.y * k.y + k.z * k.z + k.w * k.w;
            }
#pragma unroll
            for (int s = 16; s > 0; s >>= 1) {       // 32-lane segment reduce
                dot += __shfl_xor(dot, s);
                ss  += __shfl_xor(ss, s);
            }
            float sim = dot / fmaxf(sqrtf(ss), 1e-12f);
#pragma unroll
            for (int qq = 0; qq < 2; ++qq) {
                float sq = __shfl(sim, qq * 32);     // wave-uniform
                if (sq > v[15]) {
                    float cv = sq; int ci = T * 6 + 2 * w + qq;
#pragma unroll
                    for (int jj = 0; jj < 16; ++jj) {
                        if (cv > v[jj]) {
                            float tv = v[jj]; int ti = id[jj];
                            v[jj] = cv; id[jj] = ci; cv = tv; ci = ti;
                        }
                    }
                }
            }
        };

        {   // prologue: seq s0, s0+1, s0+2 -> slots 0,1,2
            int se = s0;
            stage(bid + se * NBLKS, 0);
            se = (se + 1 >= NSD) ? 0 : se + 1;
            stage(bid + se * NBLKS, 1);
            se = (se + 1 >= NSD) ? 0 : se + 1;
            stage(bid + se * NBLKS, 2);
        }
        int scur = s0;
        int spre = s0 + 3; if (spre >= NSD) spre -= NSD;

#pragma unroll 1
        for (int s = 0; s < NSD; ++s) {
            stage(bid + spre * NBLKS, (s + 3) & 3);  // unconditional (wraps)
            spre = (spre + 1 >= NSD) ? 0 : spre + 1;
            asm volatile("s_waitcnt vmcnt(12)" ::: "memory");
            __builtin_amdgcn_sched_barrier(0);
            compute(bid + scur * NBLKS, s & 3);
            __builtin_amdgcn_sched_barrier(0);
            scur = (scur + 1 >= NSD) ? 0 : scur + 1;
        }
        asm volatile("s_waitcnt vmcnt(0)" ::: "memory");
    } else {
        // ================= vector path (R2 chassis, wave 3) ===============
        const float4* q4 = (const float4*)qn;
        float4 q0 = q4[lane], q1 = q4[lane + 64];

#pragma unroll 1
        for (int base = VOFF + bid * 4; base < CAPACITY; base += VSWEEP) {
            float4 ka[4], kb[4];
#pragma unroll
            for (int j = 0; j < 4; ++j) {
                const float4* kp = (const float4*)(keys + (size_t)(base + j) * KEY_DIM);
                ka[j] = kp[lane];
                kb[j] = kp[lane + 64];
            }
            float dot[4], ss[4];
#pragma unroll
            for (int j = 0; j < 4; ++j) {
                dot[j] = ka[j].x * q0.x + ka[j].y * q0.y + ka[j].z * q0.z + ka[j].w * q0.w
                       + kb[j].x * q1.x + kb[j].y * q1.y + kb[j].z * q1.z + kb[j].w * q1.w;
                ss[j]  = ka[j].x * ka[j].x + ka[j].y * ka[j].y + ka[j].z * ka[j].z + ka[j].w * ka[j].w
                       + kb[j].x * kb[j].x + kb[j].y * kb[j].y + kb[j].z * kb[j].z + kb[j].w * kb[j].w;
            }
#pragma unroll
            for (int s = 32; s > 0; s >>= 1) {
#pragma unroll
                for (int j = 0; j < 4; ++j) {
                    dot[j] += __shfl_xor(dot[j], s);
                    ss[j]  += __shfl_xor(ss[j], s);
                }
            }
#pragma unroll
            for (int j = 0; j < 4; ++j) {
                float sim = dot[j] / fmaxf(sqrtf(ss[j]), 1e-12f);
                if (sim > v[15]) {                   // wave-uniform
                    float cv = sim; int ci = base + j;
#pragma unroll
                    for (int jj = 0; jj < 16; ++jj) {
                        if (cv > v[jj]) {
                            float tv = v[jj]; int ti = id[jj];
                            v[jj] = cv; id[jj] = ci; cv = tv; ci = ti;
                        }
                    }
                }
            }
        }
    }

    // ---- merge 4 waves' top-16 -> block top-16 ----------------------------
    if (lane == 0) {
#pragma unroll
        for (int j = 0; j < 16; ++j) { bv[w * 16 + j] = v[j]; bi[w * 16 + j] = id[j]; }
    }
    __syncthreads();
    if (w == 0) {
        float lv = bv[lane]; int li = bi[lane];
        for (int rr = 0; rr < NRET; ++rr) {
            float mv = lv; int mi = li;
#pragma unroll
            for (int s = 32; s > 0; s >>= 1) {
                float ov = __shfl_xor(mv, s); int oi = __shfl_xor(mi, s);
                if (ov > mv || (ov == mv && oi < mi)) { mv = ov; mi = oi; }
            }
            if (lane == 0) {
                cand_v[bid * NRET + rr] = mv;
                cand_i[bid * NRET + rr] = mi;
            }
            if (lv == mv && li == mi) { lv = -FLT_MAX; li = 0x7fffffff; }
        }
    }
}

// ---------------- Kernel 3: final top-16 + softmax + gather ----------------
__global__ __launch_bounds__(256) void merge_out(
        const float* __restrict__ cand_v, const int* __restrict__ cand_i,
        const float* __restrict__ values, float* __restrict__ out) {
    const int tid  = threadIdx.x;
    const int wid  = tid >> 6;
    const int lane = tid & 63;
    const int M4 = (NBLKS * NRET) / 4;           // 3072 float4 groups

    float v[16]; int id[16];
#pragma unroll
    for (int j = 0; j < 16; ++j) { v[j] = -FLT_MAX; id[j] = 0x7fffffff; }

    const float4* cv4 = (const float4*)cand_v;
    const int4*   ci4 = (const int4*)cand_i;
    for (int c = tid; c < M4; c += 256) {        // 12 iterations
        float4 cv = cv4[c]; int4 ci = ci4[c];
        float cvs[4] = {cv.x, cv.y, cv.z, cv.w};
        int   cis[4] = {ci.x, ci.y, ci.z, ci.w};
#pragma unroll
        for (int u = 0; u < 4; ++u) {
            float cu = cvs[u]; int iu = cis[u];
            if (cu > v[15]) {
#pragma unroll
                for (int j = 0; j < 16; ++j) {
                    if (cu > v[j]) {
                        float tv = v[j]; int ti = id[j];
                        v[j] = cu; id[j] = iu; cu = tv; iu = ti;
                    }
                }
            }
        }
    }

    __shared__ float sv[64];
    __shared__ int   si[64];
    for (int rr = 0; rr < NRET; ++rr) {
        float mv = v[0]; int mi = id[0];
#pragma unroll
        for (int s = 32; s > 0; s >>= 1) {
            float ov = __shfl_xor(mv, s); int oi = __shfl_xor(mi, s);
            if (ov > mv || (ov == mv && oi < mi)) { mv = ov; mi = oi; }
        }
        if (v[0] == mv && id[0] == mi) {
#pragma unroll
            for (int j = 0; j < 15; ++j) { v[j] = v[j + 1]; id[j] = id[j + 1]; }
            v[15] = -FLT_MAX; id[15] = 0x7fffffff;
        }
        if (lane == 0) { sv[wid * 16 + rr] = mv; si[wid * 16 + rr] = mi; }
    }
    __syncthreads();

    if (wid == 0) {
        float lv = sv[lane]; int li = si[lane];
        float sel_v = -FLT_MAX; int sel_i = 0;
        for (int rr = 0; rr < NRET; ++rr) {
            float mv = lv; int mi = li;
#pragma unroll
            for (int s = 32; s > 0; s >>= 1) {
                float ov = __shfl_xor(mv, s); int oi = __shfl_xor(mi, s);
                if (ov > mv || (ov == mv && oi < mi)) { mv = ov; mi = oi; }
            }
            if (lv == mv && li == mi) { lv = -FLT_MAX; li = 0x7fffffff; }
            if (lane == rr) { sel_v = mv; sel_i = mi; }
        }

        // softmax over the 16 (lane 0 holds the max: rounds are descending)
        float m0 = __shfl(sel_v, 0);
        float e = (lane < NRET) ? expf(sel_v - m0) : 0.0f;
        float denom = wave_sum(e);

        float acc0 = 0.f, acc1 = 0.f;
        for (int rr = 0; rr < NRET; ++rr) {
            float ar = __shfl(e, rr) / denom;
            int   ir = __shfl(sel_i, rr);
            const float* vr = values + (size_t)ir * VALUE_DIM;
            acc0 += ar * vr[lane];
            acc1 += ar * vr[lane + 64];
        }
        out[lane]      = acc0;
        out[lane + 64] = acc1;
    }
}

extern "C" void kernel_launch(void* const* d_in, const int* in_sizes, int n_in,
                              void* d_out, int out_size, void* d_ws, size_t ws_size,
                              hipStream_t stream) {
    const float* query  = (const float*)d_in[0];
    const float* W1     = (const float*)d_in[1];
    const float* b1     = (const float*)d_in[2];
    const float* W2     = (const float*)d_in[3];
    const float* b2     = (const float*)d_in[4];
    const float* gamma  = (const float*)d_in[5];
    const float* beta   = (const float*)d_in[6];
    const float* keys   = (const float*)d_in[7];
    const float* values = (const float*)d_in[8];
    float* out = (float*)d_out;

    float* ws = (float*)d_ws;
    float* h1     = ws;                  // 512
    float* h2     = ws + 512;            // 512
    float* qn     = ws + 1024;           // 512
    float* cand_v = ws + 2048;           // NBLKS*16 floats
    int*   cand_i = (int*)(ws + 2048 + NBLKS * NRET);

    matvec512<true ><<<128, 256, 0, stream>>>(W1, query, b1, h1);
    matvec512<false><<<128, 256, 0, stream>>>(W2, h1, b2, h2);
    ln_l2norm<<<1, 512, 0, stream>>>(h2, gamma, beta, qn);
    sim_split<<<NBLKS, 256, 0, stream>>>(keys, qn, cand_v, cand_i);
    merge_out<<<1, 256, 0, stream>>>(cand_v, cand_i, values, out);
}

// Round 14
// 271.019 us; speedup vs baseline: 1.4771x; 1.0055x over previous
//
#include <hip/hip_runtime.h>
#include <hip/hip_bf16.h>
#include <float.h>
#include <math.h>

#define KEY_DIM   512
#define VALUE_DIM 128
#define CAPACITY  500000
#define NRET      16

// hybrid sim config (R12 chassis, rebalanced 75:25 per measured path rates)
#define NBLKD     512                      // DMA-path blocks (R9 structure, ring-3)
#define NBLKV     256                      // vector-path blocks (R2 structure)
#define NBLKT     (NBLKD + NBLKV)          // 768 total
#define NSD       92                       // DMA sub-tiles per block (uniform)
#define NDROWS    (NBLKD * NSD * 8)        // 376832 rows via DMA path (75.4%)
#define ROFF      NDROWS                   // vector path offset
#define NVROWS    (CAPACITY - NDROWS)      // 123168 rows via vector path (div 4)
#define VSWEEP    (NBLKV * 4 * 4)          // 4096 rows per vector sweep
#define RING      3

#define AS3 __attribute__((address_space(3)))
#define AS1 __attribute__((address_space(1)))

__device__ __forceinline__ float wave_sum(float x) {
#pragma unroll
    for (int s = 32; s > 0; s >>= 1) x += __shfl_xor(x, s);
    return x;
}

// ---------------- Kernel 1a/1b: y[r] = act(dot(W[r,:], x) + b[r]) ----------
template <bool SILU>
__global__ __launch_bounds__(256) void matvec512(
        const float* __restrict__ W, const float* __restrict__ x,
        const float* __restrict__ b, float* __restrict__ y) {
    const int wid  = threadIdx.x >> 6;
    const int lane = threadIdx.x & 63;
    const int r = blockIdx.x * 4 + wid;          // 0..511

    const float4* Wr = (const float4*)(W + (size_t)r * KEY_DIM);
    const float4* xv = (const float4*)x;

    float4 w0 = Wr[lane], w1 = Wr[lane + 64];
    float4 x0 = xv[lane], x1 = xv[lane + 64];

    float dot = w0.x * x0.x + w0.y * x0.y + w0.z * x0.z + w0.w * x0.w
              + w1.x * x1.x + w1.y * x1.y + w1.z * x1.z + w1.w * x1.w;
    dot = wave_sum(dot);

    if (lane == 0) {
        float v = dot + b[r];
        if (SILU) v = v / (1.0f + expf(-v));     // silu = x*sigmoid(x)
        y[r] = v;
    }
}

// ---------------- Kernel 1c: LayerNorm + l2-normalize -> qn[512] -----------
__global__ __launch_bounds__(512) void ln_l2norm(
        const float* __restrict__ h, const float* __restrict__ gamma,
        const float* __restrict__ beta, float* __restrict__ qn) {
    __shared__ float s1[8], s2[8];
    const int t = threadIdx.x;                   // 512 threads = 8 waves
    const int wid = t >> 6, lane = t & 63;

    float x = h[t];
    float a = x, bb = x * x;
#pragma unroll
    for (int s = 32; s > 0; s >>= 1) { a += __shfl_xor(a, s); bb += __shfl_xor(bb, s); }
    if (lane == 0) { s1[wid] = a; s2[wid] = bb; }
    __syncthreads();

    float suma = 0.f, sumb = 0.f;
#pragma unroll
    for (int i = 0; i < 8; ++i) { suma += s1[i]; sumb += s2[i]; }
    float mu  = suma * (1.0f / KEY_DIM);
    float var = sumb * (1.0f / KEY_DIM) - mu * mu;      // biased, like torch LN
    float ln  = (x - mu) / sqrtf(var + 1e-5f) * gamma[t] + beta[t];

    float c = wave_sum(ln * ln);
    __syncthreads();
    if (lane == 0) s1[wid] = c;
    __syncthreads();
    float ss = 0.f;
#pragma unroll
    for (int i = 0; i < 8; ++i) ss += s1[i];
    float n = fmaxf(sqrtf(ss), 1e-12f);
    qn[t] = ln / n;
}

// ---------------- Kernel 2: HYBRID cosine sim + per-block top-16 -----------
// R12 chassis, rebalanced. Two concurrent read paths splitting the key range:
//  - bid%3<2 (512 blocks): R9 DMA structure (global_load_lds ring-3, 48 KB
//    LDS, wave-private sub-buffers, counted vmcnt, no barriers) ~4.4 TB/s.
//  - bid%3==2 (256 blocks): R2 vector structure (4 batched rows/iter, plain
//    float4 loads, butterfly reduce) ~1.5 TB/s at 4 waves/CU (self-limited).
// Split 75.4 : 24.6 matches measured rates so both sides finish together.
__global__ __launch_bounds__(256) void sim_hybrid(
        const float* __restrict__ keys, const float* __restrict__ qn,
        float* __restrict__ cand_v, int* __restrict__ cand_i) {
    __shared__ float kl[RING][8][KEY_DIM];           // 48 KB (DMA blocks only)
    __shared__ float bv[64];
    __shared__ int   bi[64];

    const int tid  = threadIdx.x;
    const int w    = tid >> 6;
    const int lane = tid & 63;
    const int bid  = blockIdx.x;
    const int r3   = bid % 3;

    // wave-uniform top-16
    float v[16]; int id[16];
#pragma unroll
    for (int j = 0; j < 16; ++j) { v[j] = -FLT_MAX; id[j] = 0x7fffffff; }

    if (r3 < 2) {
        // ================= DMA path (R9 chassis, ring-3) ==================
        const int d    = (bid / 3) * 2 + r3;         // 0..511
        const int m    = lane & 31;
        const int rsel = lane >> 5;
        const int s0   = (d * 7919) % NSD;

        float4 qr[4];
        {
            const float4* q4 = (const float4*)qn;
#pragma unroll
            for (int j = 0; j < 4; ++j) qr[j] = q4[4 * m + j];
        }
        int srcoff0, srcoff1;
        {
            int p0 = lane,      g0 = p0 >> 2, sl0 = p0 & 3;
            int p1 = 64 + lane, g1 = p1 >> 2, sl1 = p1 & 3;
            srcoff0 = (4 * g0 + ((sl0 - (g0 >> 1)) & 3)) * 16;
            srcoff1 = (4 * g1 + ((sl1 - (g1 >> 1)) & 3)) * 16;
        }
        int roff[4];
#pragma unroll
        for (int j = 0; j < 4; ++j) roff[j] = (4 * m + ((j + (m >> 1)) & 3)) * 16;

        auto stage = [&](int G, int slot) {
#pragma unroll
            for (int i = 0; i < 4; ++i) {
                const int rl = 2 * w + (i >> 1);
                const int h  = i & 1;
                const char* gp = (const char*)(keys + ((size_t)G * 8 + rl) * KEY_DIM)
                                 + (h ? srcoff1 : srcoff0);
                float* lp = &kl[slot][rl][h * 256];  // wave-uniform base
                __builtin_amdgcn_global_load_lds((const AS1 float*)gp, (AS3 float*)lp,
                                                 16, 0, 0);
            }
        };
        auto compute = [&](int G, int slot) {
            const char* rowbase = (const char*)&kl[slot][2 * w + rsel][0];
            float dot = 0.f, ss = 0.f;
#pragma unroll
            for (int j = 0; j < 4; ++j) {
                float4 k = *(const float4*)(rowbase + roff[j]);
                float4 q = qr[j];
                dot += k.x * q.x + k.y * q.y + k.z * q.z + k.w * q.w;
                ss  += k.x * k.x + k.y * k.y + k.z * k.z + k.w * k.w;
            }
#pragma unroll
            for (int s = 16; s > 0; s >>= 1) {
                dot += __shfl_xor(dot, s);
                ss  += __shfl_xor(ss, s);
            }
            float sim = dot / fmaxf(sqrtf(ss), 1e-12f);
#pragma unroll
            for (int q = 0; q < 2; ++q) {
                float sq = __shfl(sim, q * 32);      // wave-uniform
                if (sq > v[15]) {
                    float cv = sq; int ci = G * 8 + 2 * w + q;
#pragma unroll
                    for (int jj = 0; jj < 16; ++jj) {
                        if (cv > v[jj]) {
                            float tv = v[jj]; int ti = id[jj];
                            v[jj] = cv; id[jj] = ci; cv = tv; ci = ti;
                        }
                    }
                }
            }
        };

        {   // prologue: seq s0, s0+1 -> slots 0,1
            int se = s0;
            stage(d + se * NBLKD, 0);
            se = (se + 1 >= NSD) ? 0 : se + 1;
            stage(d + se * NBLKD, 1);
        }
        int scur = s0;
        int spre = s0 + 2; if (spre >= NSD) spre -= NSD;

#pragma unroll 1
        for (int s = 0; s < NSD; ++s) {
            stage(d + spre * NBLKD, (s + 2) % 3);    // unconditional (wraps)
            spre = (spre + 1 >= NSD) ? 0 : spre + 1;
            asm volatile("s_waitcnt vmcnt(8)" ::: "memory");
            __builtin_amdgcn_sched_barrier(0);
            compute(d + scur * NBLKD, s % 3);
            __builtin_amdgcn_sched_barrier(0);
            scur = (scur + 1 >= NSD) ? 0 : scur + 1;
        }
        asm volatile("s_waitcnt vmcnt(0)" ::: "memory");
    } else {
        // ================= vector path (R2 chassis) =======================
        const int gw = (bid / 3) * 4 + w;            // 0..1023
        const float4* q4 = (const float4*)qn;
        float4 q0 = q4[lane], q1 = q4[lane + 64];

#pragma unroll 1
        for (int base = gw * 4; base < NVROWS; base += VSWEEP) {  // 4096/sweep
            float4 ka[4], kb[4];
#pragma unroll
            for (int j = 0; j < 4; ++j) {
                const float4* kp = (const float4*)(keys + (size_t)(ROFF + base + j) * KEY_DIM);
                ka[j] = kp[lane];
                kb[j] = kp[lane + 64];
            }
            float dot[4], ss[4];
#pragma unroll
            for (int j = 0; j < 4; ++j) {
                dot[j] = ka[j].x * q0.x + ka[j].y * q0.y + ka[j].z * q0.z + ka[j].w * q0.w
                       + kb[j].x * q1.x + kb[j].y * q1.y + kb[j].z * q1.z + kb[j].w * q1.w;
                ss[j]  = ka[j].x * ka[j].x + ka[j].y * ka[j].y + ka[j].z * ka[j].z + ka[j].w * ka[j].w
                       + kb[j].x * kb[j].x + kb[j].y * kb[j].y + kb[j].z * kb[j].z + kb[j].w * kb[j].w;
            }
#pragma unroll
            for (int s = 32; s > 0; s >>= 1) {
#pragma unroll
                for (int j = 0; j < 4; ++j) {
                    dot[j] += __shfl_xor(dot[j], s);
                    ss[j]  += __shfl_xor(ss[j], s);
                }
            }
#pragma unroll
            for (int j = 0; j < 4; ++j) {
                float sim = dot[j] / fmaxf(sqrtf(ss[j]), 1e-12f);
                if (sim > v[15]) {                   // wave-uniform
                    float cv = sim; int ci = ROFF + base + j;
#pragma unroll
                    for (int jj = 0; jj < 16; ++jj) {
                        if (cv > v[jj]) {
                            float tv = v[jj]; int ti = id[jj];
                            v[jj] = cv; id[jj] = ci; cv = tv; ci = ti;
                        }
                    }
                }
            }
        }
    }

    // ---- merge 4 waves' top-16 -> block top-16 ----------------------------
    if (lane == 0) {
#pragma unroll
        for (int j = 0; j < 16; ++j) { bv[w * 16 + j] = v[j]; bi[w * 16 + j] = id[j]; }
    }
    __syncthreads();
    if (w == 0) {
        const int cidx = (r3 < 2) ? ((bid / 3) * 2 + r3) : (NBLKD + bid / 3);
        float lv = bv[lane]; int li = bi[lane];
        for (int rr = 0; rr < NRET; ++rr) {
            float mv = lv; int mi = li;
#pragma unroll
            for (int s = 32; s > 0; s >>= 1) {
                float ov = __shfl_xor(mv, s); int oi = __shfl_xor(mi, s);
                if (ov > mv || (ov == mv && oi < mi)) { mv = ov; mi = oi; }
            }
            if (lane == 0) {
                cand_v[cidx * NRET + rr] = mv;
                cand_i[cidx * NRET + rr] = mi;
            }
            if (lv == mv && li == mi) { lv = -FLT_MAX; li = 0x7fffffff; }
        }
    }
}

// ---------------- Kernel 3: final top-16 + softmax + gather ----------------
__global__ __launch_bounds__(256) void merge_out(
        const float* __restrict__ cand_v, const int* __restrict__ cand_i,
        const float* __restrict__ values, float* __restrict__ out) {
    const int tid  = threadIdx.x;
    const int wid  = tid >> 6;
    const int lane = tid & 63;
    const int M4 = (NBLKT * NRET) / 4;           // 3072 float4 groups

    float v[16]; int id[16];
#pragma unroll
    for (int j = 0; j < 16; ++j) { v[j] = -FLT_MAX; id[j] = 0x7fffffff; }

    const float4* cv4 = (const float4*)cand_v;
    const int4*   ci4 = (const int4*)cand_i;
    for (int c = tid; c < M4; c += 256) {        // 12 iterations
        float4 cv = cv4[c]; int4 ci = ci4[c];
        float cvs[4] = {cv.x, cv.y, cv.z, cv.w};
        int   cis[4] = {ci.x, ci.y, ci.z, ci.w};
#pragma unroll
        for (int u = 0; u < 4; ++u) {
            float cu = cvs[u]; int iu = cis[u];
            if (cu > v[15]) {
#pragma unroll
                for (int j = 0; j < 16; ++j) {
                    if (cu > v[j]) {
                        float tv = v[j]; int ti = id[j];
                        v[j] = cu; id[j] = iu; cu = tv; iu = ti;
                    }
                }
            }
        }
    }

    __shared__ float sv[64];
    __shared__ int   si[64];
    for (int rr = 0; rr < NRET; ++rr) {
        float mv = v[0]; int mi = id[0];
#pragma unroll
        for (int s = 32; s > 0; s >>= 1) {
            float ov = __shfl_xor(mv, s); int oi = __shfl_xor(mi, s);
            if (ov > mv || (ov == mv && oi < mi)) { mv = ov; mi = oi; }
        }
        if (v[0] == mv && id[0] == mi) {
#pragma unroll
            for (int j = 0; j < 15; ++j) { v[j] = v[j + 1]; id[j] = id[j + 1]; }
            v[15] = -FLT_MAX; id[15] = 0x7fffffff;
        }
        if (lane == 0) { sv[wid * 16 + rr] = mv; si[wid * 16 + rr] = mi; }
    }
    __syncthreads();

    if (wid == 0) {
        float lv = sv[lane]; int li = si[lane];
        float sel_v = -FLT_MAX; int sel_i = 0;
        for (int rr = 0; rr < NRET; ++rr) {
            float mv = lv; int mi = li;
#pragma unroll
            for (int s = 32; s > 0; s >>= 1) {
                float ov = __shfl_xor(mv, s); int oi = __shfl_xor(mi, s);
                if (ov > mv || (ov == mv && oi < mi)) { mv = ov; mi = oi; }
            }
            if (lv == mv && li == mi) { lv = -FLT_MAX; li = 0x7fffffff; }
            if (lane == rr) { sel_v = mv; sel_i = mi; }
        }

        // softmax over the 16 (lane 0 holds the max: rounds are descending)
        float m0 = __shfl(sel_v, 0);
        float e = (lane < NRET) ? expf(sel_v - m0) : 0.0f;
        float denom = wave_sum(e);

        float acc0 = 0.f, acc1 = 0.f;
        for (int rr = 0; rr < NRET; ++rr) {
            float ar = __shfl(e, rr) / denom;
            int   ir = __shfl(sel_i, rr);
            const float* vr = values + (size_t)ir * VALUE_DIM;
            acc0 += ar * vr[lane];
            acc1 += ar * vr[lane + 64];
        }
        out[lane]      = acc0;
        out[lane + 64] = acc1;
    }
}

extern "C" void kernel_launch(void* const* d_in, const int* in_sizes, int n_in,
                              void* d_out, int out_size, void* d_ws, size_t ws_size,
                              hipStream_t stream) {
    const float* query  = (const float*)d_in[0];
    const float* W1     = (const float*)d_in[1];
    const float* b1     = (const float*)d_in[2];
    const float* W2     = (const float*)d_in[3];
    const float* b2     = (const float*)d_in[4];
    const float* gamma  = (const float*)d_in[5];
    const float* beta   = (const float*)d_in[6];
    const float* keys   = (const float*)d_in[7];
    const float* values = (const float*)d_in[8];
    float* out = (float*)d_out;

    float* ws = (float*)d_ws;
    float* h1     = ws;                  // 512
    float* h2     = ws + 512;            // 512
    float* qn     = ws + 1024;           // 512
    float* cand_v = ws + 2048;           // NBLKT*16 floats
    int*   cand_i = (int*)(ws + 2048 + NBLKT * NRET);

    matvec512<true ><<<128, 256, 0, stream>>>(W1, query, b1, h1);
    matvec512<false><<<128, 256, 0, stream>>>(W2, h1, b2, h2);
    ln_l2norm<<<1, 512, 0, stream>>>(h2, gamma, beta, qn);
    sim_hybrid<<<NBLKT, 256, 0, stream>>>(keys, qn, cand_v, cand_i);
    merge_out<<<1, 256, 0, stream>>>(cand_v, cand_i, values, out);
}